// Round 6
// baseline (72.323 us; speedup 1.0000x reference)
//
#include <hip/hip_runtime.h>

// Problem constants (from reference)
#define B 8
#define C 64
#define H 64
#define W 64
#define K 5
#define PAD 2
#define HW (H * W)          // 4096
#define CHW (C * HW)        // 262144
#define TOT (B * CHW)       // 2097152

// attn tiling: block = 16 rows x 64 cols of one (b,c) plane
#define TROWS 16
#define SROWS (TROWS + 2 * PAD)   // 20 staged rows
#define SCOLS 72                  // 64 + 2*PAD, padded to 72 for 16B row alignment
#define NSLOT2 (SROWS * (SCOLS / 2))  // 720 float2 slots per plane

// ---------------------------------------------------------------------------
// Pass 1 (v2): one-pass LDS-staged 1x1 conv producing ALL 192 outputs.
// Block = one image row (b,h): 64 pixels. Stage x[b, 0..63, h, 0..63]
// (16 KB) into LDS via coalesced float4 (4 per thread). Thread t:
// pixel w = t&63, group g = t>>6; computes outputs [g*48, g*48+48) as
// 3 chunks of 16 accumulators. xr[64] loaded from LDS once (lane-stride-1,
// conflict-free), then pure FMA. x read from global exactly once (8 MB
// total). W reads wave-uniform -> scalar loads. 512 blocks = 2/CU.
// ---------------------------------------------------------------------------
__global__ __launch_bounds__(256) void qkv_kernel(
    const float* __restrict__ x,
    const float* __restrict__ Wq,
    const float* __restrict__ Wk,
    const float* __restrict__ Wv,
    float* __restrict__ qb,
    float* __restrict__ kb,
    float* __restrict__ vb)
{
    __shared__ __align__(16) float sx[C][W];   // 16 KB

    const int tile = blockIdx.x;       // b*H + h
    const int b = tile >> 6;
    const int h = tile & 63;
    const int t = threadIdx.x;

    // stage: 1024 float4 slots, 4 per thread, coalesced
    const float* xbase = x + b * CHW + h * W;
#pragma unroll
    for (int i = 0; i < 4; ++i) {
        const int f = t + i * 256;     // float4 slot id
        const int c = f >> 4;          // channel
        const int w4 = (f & 15) << 2;  // col base
        const float4 v = *(const float4*)(xbase + c * HW + w4);
        *(float4*)&sx[c][w4] = v;
    }
    __syncthreads();

    const int w = t & 63;
    const int g = t >> 6;              // 0..3 -> outputs g*48 .. g*48+47

    float xr[C];
#pragma unroll
    for (int c = 0; c < C; ++c) xr[c] = sx[c][w];

    const int obase = b * CHW + h * W + w;

#pragma unroll
    for (int cc = 0; cc < 3; ++cc) {
        const int og = g * 48 + cc * 16;         // global output channel base
        const float* Wm;
        float* ob;
        if (og < 64)       { Wm = Wq; ob = qb; }
        else if (og < 128) { Wm = Wk; ob = kb; }
        else               { Wm = Wv; ob = vb; }
        const int ol = og & 63;                  // local output channel base
        Wm += ol * C;

        float acc[16];
#pragma unroll
        for (int o = 0; o < 16; ++o) acc[o] = 0.f;

#pragma unroll
        for (int c = 0; c < C; ++c) {
            const float xv = xr[c];
#pragma unroll
            for (int o = 0; o < 16; ++o)
                acc[o] = fmaf(Wm[o * C + c], xv, acc[o]);
        }

        float* op = ob + obase + ol * HW;
#pragma unroll
        for (int o = 0; o < 16; ++o) op[o * HW] = acc[o];
    }
}

// ---------------------------------------------------------------------------
// Pass 2: per-channel 5x5 windowed softmax attention, LDS-staged.
// (byte-identical to round-5 version — kept fixed for clean attribution)
// ---------------------------------------------------------------------------
__global__ __launch_bounds__(256) void attn_kernel(
    const float* __restrict__ qb,
    const float* __restrict__ kb,
    const float* __restrict__ vb,
    const float* __restrict__ rel_h,
    const float* __restrict__ rel_w,
    float* __restrict__ out)
{
    __shared__ __align__(16) float sk[SROWS][SCOLS];
    __shared__ __align__(16) float sv[SROWS][SCOLS];

    const int bid = blockIdx.x;
    const int pl  = bid >> 2;          // b*C + c
    const int h0  = (bid & 3) * TROWS;
    const int c   = pl & 63;
    const int t   = threadIdx.x;

    const float* kp = kb + pl * HW;
    const float* vp = vb + pl * HW;

    // ---- stage: 2 planes * 720 float2 slots ----
    for (int idx = t; idx < 2 * NSLOT2; idx += 256) {
        const int p   = (idx >= NSLOT2);
        const int rem = p ? idx - NSLOT2 : idx;
        const int row = rem / (SCOLS / 2);
        const int c2  = rem - row * (SCOLS / 2);   // float2 col 0..35
        const int g   = h0 + row - PAD;            // global row
        float2 val = make_float2(0.f, 0.f);
        if (((unsigned)g < (unsigned)H) & (c2 >= 1) & (c2 <= 32)) {
            const float* src = (p ? vp : kp) + g * W + (c2 * 2 - 2);
            val = *(const float2*)src;
        }
        float* dst = (p ? &sv[0][0] : &sk[0][0]) + row * SCOLS + c2 * 2;
        *(float2*)dst = val;
    }
    __syncthreads();

    // ---- compute: 1 quad (4 px) per thread ----
    const int lr = t >> 4;             // local row 0..15
    const int w0 = (t & 15) << 2;      // col base 0,4,..,60
    const int h  = h0 + lr;

    const float4 qv = *(const float4*)(qb + pl * HW + h * W + w0);
    const float qx[4] = {qv.x, qv.y, qv.z, qv.w};

    const bool is_h = (c < (C / 2));
    const float* rp = is_h ? (rel_h + c * K) : (rel_w + (c - C / 2) * K);
    float r[K];
#pragma unroll
    for (int u = 0; u < K; ++u) r[u] = rp[u];

    float den[4] = {0.f, 0.f, 0.f, 0.f};
    float num[4] = {0.f, 0.f, 0.f, 0.f};

    if (is_h) {
#pragma unroll
        for (int i = 0; i < K; ++i) {
            const float4 ka = *(const float4*)&sk[lr + i][w0];
            const float4 kc = *(const float4*)&sk[lr + i][w0 + 4];
            const float4 va = *(const float4*)&sv[lr + i][w0];
            const float4 vc = *(const float4*)&sv[lr + i][w0 + 4];
            const float kr[8] = {ka.x, ka.y, ka.z, ka.w, kc.x, kc.y, kc.z, kc.w};
            const float vr[8] = {va.x, va.y, va.z, va.w, vc.x, vc.y, vc.z, vc.w};
            float qri[4];
#pragma unroll
            for (int px = 0; px < 4; ++px) qri[px] = qx[px] * r[i];
#pragma unroll
            for (int j = 0; j < K; ++j) {
#pragma unroll
                for (int px = 0; px < 4; ++px) {
                    const float e = __expf(fmaf(qx[px], kr[px + j], qri[px]));
                    den[px] += e;
                    num[px] = fmaf(e, vr[px + j], num[px]);
                }
            }
        }
    } else {
        float qrj[4][K];
#pragma unroll
        for (int px = 0; px < 4; ++px)
#pragma unroll
            for (int j = 0; j < K; ++j) qrj[px][j] = qx[px] * r[j];
#pragma unroll
        for (int i = 0; i < K; ++i) {
            const float4 ka = *(const float4*)&sk[lr + i][w0];
            const float4 kc = *(const float4*)&sk[lr + i][w0 + 4];
            const float4 va = *(const float4*)&sv[lr + i][w0];
            const float4 vc = *(const float4*)&sv[lr + i][w0 + 4];
            const float kr[8] = {ka.x, ka.y, ka.z, ka.w, kc.x, kc.y, kc.z, kc.w};
            const float vr[8] = {va.x, va.y, va.z, va.w, vc.x, vc.y, vc.z, vc.w};
#pragma unroll
            for (int j = 0; j < K; ++j) {
#pragma unroll
                for (int px = 0; px < 4; ++px) {
                    const float e = __expf(fmaf(qx[px], kr[px + j], qrj[px][j]));
                    den[px] += e;
                    num[px] = fmaf(e, vr[px + j], num[px]);
                }
            }
        }
    }

    float4 o;
    o.x = num[0] * __builtin_amdgcn_rcpf(den[0]);
    o.y = num[1] * __builtin_amdgcn_rcpf(den[1]);
    o.z = num[2] * __builtin_amdgcn_rcpf(den[2]);
    o.w = num[3] * __builtin_amdgcn_rcpf(den[3]);
    *(float4*)(out + pl * HW + h * W + w0) = o;
}

// ---------------------------------------------------------------------------
extern "C" void kernel_launch(void* const* d_in, const int* in_sizes, int n_in,
                              void* d_out, int out_size, void* d_ws, size_t ws_size,
                              hipStream_t stream)
{
    const float* x     = (const float*)d_in[0];
    const float* Wq    = (const float*)d_in[1];
    const float* Wk    = (const float*)d_in[2];
    const float* Wv    = (const float*)d_in[3];
    const float* rel_h = (const float*)d_in[4];
    const float* rel_w = (const float*)d_in[5];

    float* qb = (float*)d_ws;        // [B,C,64,64]  8 MB
    float* kb = qb + TOT;            // [B,C,64,64]  8 MB
    float* vb = kb + TOT;            // [B,C,64,64]  8 MB

    qkv_kernel<<<B * H, 256, 0, stream>>>(x, Wq, Wk, Wv, qb, kb, vb);

    attn_kernel<<<B * C * 4, 256, 0, stream>>>(qb, kb, vb, rel_h, rel_w,
                                               (float*)d_out);
}

// Round 7
// 71.118 us; speedup vs baseline: 1.0170x; 1.0170x over previous
//
#include <hip/hip_runtime.h>

// Problem constants (from reference)
#define B 8
#define C 64
#define H 64
#define W 64
#define K 5
#define PAD 2
#define HW (H * W)          // 4096
#define CHW (C * HW)        // 262144
#define TOT (B * CHW)       // 2097152

// attn tiling: block = 16 rows x 64 cols of one (b,c) plane
#define TROWS 16
#define SROWS (TROWS + 2 * PAD)   // 20 staged rows
#define SCOLS 72                  // 64 + 2*PAD, padded to 72 for 16B row alignment
#define NSLOT2 (SROWS * (SCOLS / 2))  // 720 float2 slots per plane

// ---------------------------------------------------------------------------
// Pass 1 (v3): one-pass LDS-staged 1x1 conv, SCALAR weight path.
// Block = one image row (b,h): 64 pixels, 4 waves. Stage x[b,:,h,:] (16 KB)
// into LDS (coalesced float4). Wave wv (= readfirstlane(t>>6), provably
// wave-uniform -> weight selection + all W addresses are SCALAR: s_load
// batches, FMA consumes SGPR operand directly) computes output channels
// [wv*48, wv*48+48) for its 64 pixels, 3 chunks of 16. o-outer/c-inner
// makes each o's 64 weights consecutive -> s_load_dwordx16. 16 independent
// acc chains hide FMA latency. x read from global exactly once.
// ---------------------------------------------------------------------------
__global__ __launch_bounds__(256) void qkv_kernel(
    const float* __restrict__ x,
    const float* __restrict__ Wq,
    const float* __restrict__ Wk,
    const float* __restrict__ Wv,
    float* __restrict__ qb,
    float* __restrict__ kb,
    float* __restrict__ vb)
{
    __shared__ __align__(16) float sx[C][W];   // 16 KB

    const int tile = blockIdx.x;       // b*H + h
    const int b = tile >> 6;
    const int h = tile & 63;
    const int t = threadIdx.x;

    // stage: 1024 float4 slots, 4 per thread, coalesced
    const float* xbase = x + b * CHW + h * W;
#pragma unroll
    for (int i = 0; i < 4; ++i) {
        const int f = t + i * 256;     // float4 slot id
        const int c = f >> 4;          // channel
        const int w4 = (f & 15) << 2;  // col base
        const float4 v = *(const float4*)(xbase + c * HW + w4);
        *(float4*)&sx[c][w4] = v;
    }
    __syncthreads();

    const int w  = t & 63;
    // wave-uniform chunk-group id: readfirstlane makes it SGPR-provable
    const int wv = __builtin_amdgcn_readfirstlane(t >> 6);   // 0..3

    float xr[C];
#pragma unroll
    for (int c = 0; c < C; ++c) xr[c] = sx[c][w];

    const int obase = b * CHW + h * W + w;

#pragma unroll
    for (int cc = 0; cc < 3; ++cc) {
        const int og = wv * 48 + cc * 16;        // uniform output-channel base
        const float* Wm;
        float* ob;
        if (og < 64)       { Wm = Wq; ob = qb; }
        else if (og < 128) { Wm = Wk; ob = kb; }
        else               { Wm = Wv; ob = vb; }
        const int ol = og & 63;                  // local output channel base
        Wm += ol * C;

        float acc[16];
#pragma unroll
        for (int o = 0; o < 16; ++o) acc[o] = 0.f;

        // o-outer / c-inner: weights for fixed o are 64 consecutive dwords
        // (scalar address) -> s_load_dwordx16; FMA = v_fmac(acc, s_w, v_x)
#pragma unroll
        for (int o = 0; o < 16; ++o) {
            const float* wrow = Wm + o * C;
#pragma unroll
            for (int c = 0; c < C; ++c)
                acc[o] = fmaf(wrow[c], xr[c], acc[o]);
        }

        float* op = ob + obase + ol * HW;
#pragma unroll
        for (int o = 0; o < 16; ++o) op[o * HW] = acc[o];
    }
}

// ---------------------------------------------------------------------------
// Pass 2: per-channel 5x5 windowed softmax attention, LDS-staged.
// (byte-identical to round-5 version — kept fixed for clean attribution)
// ---------------------------------------------------------------------------
__global__ __launch_bounds__(256) void attn_kernel(
    const float* __restrict__ qb,
    const float* __restrict__ kb,
    const float* __restrict__ vb,
    const float* __restrict__ rel_h,
    const float* __restrict__ rel_w,
    float* __restrict__ out)
{
    __shared__ __align__(16) float sk[SROWS][SCOLS];
    __shared__ __align__(16) float sv[SROWS][SCOLS];

    const int bid = blockIdx.x;
    const int pl  = bid >> 2;          // b*C + c
    const int h0  = (bid & 3) * TROWS;
    const int c   = pl & 63;
    const int t   = threadIdx.x;

    const float* kp = kb + pl * HW;
    const float* vp = vb + pl * HW;

    // ---- stage: 2 planes * 720 float2 slots ----
    for (int idx = t; idx < 2 * NSLOT2; idx += 256) {
        const int p   = (idx >= NSLOT2);
        const int rem = p ? idx - NSLOT2 : idx;
        const int row = rem / (SCOLS / 2);
        const int c2  = rem - row * (SCOLS / 2);   // float2 col 0..35
        const int g   = h0 + row - PAD;            // global row
        float2 val = make_float2(0.f, 0.f);
        if (((unsigned)g < (unsigned)H) & (c2 >= 1) & (c2 <= 32)) {
            const float* src = (p ? vp : kp) + g * W + (c2 * 2 - 2);
            val = *(const float2*)src;
        }
        float* dst = (p ? &sv[0][0] : &sk[0][0]) + row * SCOLS + c2 * 2;
        *(float2*)dst = val;
    }
    __syncthreads();

    // ---- compute: 1 quad (4 px) per thread ----
    const int lr = t >> 4;             // local row 0..15
    const int w0 = (t & 15) << 2;      // col base 0,4,..,60
    const int h  = h0 + lr;

    const float4 qv = *(const float4*)(qb + pl * HW + h * W + w0);
    const float qx[4] = {qv.x, qv.y, qv.z, qv.w};

    const bool is_h = (c < (C / 2));
    const float* rp = is_h ? (rel_h + c * K) : (rel_w + (c - C / 2) * K);
    float r[K];
#pragma unroll
    for (int u = 0; u < K; ++u) r[u] = rp[u];

    float den[4] = {0.f, 0.f, 0.f, 0.f};
    float num[4] = {0.f, 0.f, 0.f, 0.f};

    if (is_h) {
#pragma unroll
        for (int i = 0; i < K; ++i) {
            const float4 ka = *(const float4*)&sk[lr + i][w0];
            const float4 kc = *(const float4*)&sk[lr + i][w0 + 4];
            const float4 va = *(const float4*)&sv[lr + i][w0];
            const float4 vc = *(const float4*)&sv[lr + i][w0 + 4];
            const float kr[8] = {ka.x, ka.y, ka.z, ka.w, kc.x, kc.y, kc.z, kc.w};
            const float vr[8] = {va.x, va.y, va.z, va.w, vc.x, vc.y, vc.z, vc.w};
            float qri[4];
#pragma unroll
            for (int px = 0; px < 4; ++px) qri[px] = qx[px] * r[i];
#pragma unroll
            for (int j = 0; j < K; ++j) {
#pragma unroll
                for (int px = 0; px < 4; ++px) {
                    const float e = __expf(fmaf(qx[px], kr[px + j], qri[px]));
                    den[px] += e;
                    num[px] = fmaf(e, vr[px + j], num[px]);
                }
            }
        }
    } else {
        float qrj[4][K];
#pragma unroll
        for (int px = 0; px < 4; ++px)
#pragma unroll
            for (int j = 0; j < K; ++j) qrj[px][j] = qx[px] * r[j];
#pragma unroll
        for (int i = 0; i < K; ++i) {
            const float4 ka = *(const float4*)&sk[lr + i][w0];
            const float4 kc = *(const float4*)&sk[lr + i][w0 + 4];
            const float4 va = *(const float4*)&sv[lr + i][w0];
            const float4 vc = *(const float4*)&sv[lr + i][w0 + 4];
            const float kr[8] = {ka.x, ka.y, ka.z, ka.w, kc.x, kc.y, kc.z, kc.w};
            const float vr[8] = {va.x, va.y, va.z, va.w, vc.x, vc.y, vc.z, vc.w};
#pragma unroll
            for (int j = 0; j < K; ++j) {
#pragma unroll
                for (int px = 0; px < 4; ++px) {
                    const float e = __expf(fmaf(qx[px], kr[px + j], qrj[px][j]));
                    den[px] += e;
                    num[px] = fmaf(e, vr[px + j], num[px]);
                }
            }
        }
    }

    float4 o;
    o.x = num[0] * __builtin_amdgcn_rcpf(den[0]);
    o.y = num[1] * __builtin_amdgcn_rcpf(den[1]);
    o.z = num[2] * __builtin_amdgcn_rcpf(den[2]);
    o.w = num[3] * __builtin_amdgcn_rcpf(den[3]);
    *(float4*)(out + pl * HW + h * W + w0) = o;
}

// ---------------------------------------------------------------------------
extern "C" void kernel_launch(void* const* d_in, const int* in_sizes, int n_in,
                              void* d_out, int out_size, void* d_ws, size_t ws_size,
                              hipStream_t stream)
{
    const float* x     = (const float*)d_in[0];
    const float* Wq    = (const float*)d_in[1];
    const float* Wk    = (const float*)d_in[2];
    const float* Wv    = (const float*)d_in[3];
    const float* rel_h = (const float*)d_in[4];
    const float* rel_w = (const float*)d_in[5];

    float* qb = (float*)d_ws;        // [B,C,64,64]  8 MB
    float* kb = qb + TOT;            // [B,C,64,64]  8 MB
    float* vb = kb + TOT;            // [B,C,64,64]  8 MB

    qkv_kernel<<<B * H, 256, 0, stream>>>(x, Wq, Wk, Wv, qb, kb, vb);

    attn_kernel<<<B * C * 4, 256, 0, stream>>>(qb, kb, vb, rel_h, rel_w,
                                               (float*)d_out);
}

// Round 8
// 45.034 us; speedup vs baseline: 1.6060x; 1.5792x over previous
//
#include <hip/hip_runtime.h>

// Problem constants (from reference)
#define B 8
#define C 64
#define H 64
#define W 64
#define K 5
#define PAD 2
#define HW (H * W)          // 4096
#define CHW (C * HW)        // 262144
#define TOT (B * CHW)       // 2097152

// attn tiling: block = 16 rows x 64 cols of one (b,c) plane
#define TROWS 16
#define SROWS (TROWS + 2 * PAD)   // 20 staged rows
#define SCOLS 72                  // 64 + 2*PAD, padded to 72 for 16B row alignment
#define NSLOT2 (SROWS * (SCOLS / 2))  // 720 float2 slots per plane

// ---------------------------------------------------------------------------
// Pass 1 (v4): LDS-staged 1x1 conv, latency-hiding grid.
// grid = (B*H, 3): blockIdx.y = matrix (block-uniform -> all weight/output
// selection is pure scalar, no divergence, no per-row select). Block stages
// x[b,:,h,:] (16 KB) into LDS (coalesced float4). Thread t: pixel w = t&63,
// sub = readfirstlane(t>>6) (wave-uniform -> SGPR) -> computes o-rows
// [sub*16, sub*16+16). Weights via s_load (scalar addresses, consecutive
// 64 dwords per row); 4 partial accumulators per row break the FMA dep
// chain. 1536 blocks = 6 blocks/CU = 24 waves/CU resident (LDS 96 KB/CU)
// -> 6 waves/SIMD to hide s_load + HBM latency (r7 had only 2).
// ---------------------------------------------------------------------------
__global__ __launch_bounds__(256) void qkv_kernel(
    const float* __restrict__ x,
    const float* __restrict__ Wq,
    const float* __restrict__ Wk,
    const float* __restrict__ Wv,
    float* __restrict__ qb,
    float* __restrict__ kb,
    float* __restrict__ vb)
{
    __shared__ __align__(16) float sx[C][W];   // 16 KB

    const int tile = blockIdx.x;       // b*H + h
    const int b = tile >> 6;
    const int h = tile & 63;
    const int t = threadIdx.x;

    // stage: 1024 float4 slots, 4 per thread, coalesced
    const float* xbase = x + b * CHW + h * W;
#pragma unroll
    for (int i = 0; i < 4; ++i) {
        const int f  = t + i * 256;    // float4 slot id
        const int c  = f >> 4;         // channel
        const int w4 = (f & 15) << 2;  // col base
        *(float4*)&sx[c][w4] = *(const float4*)(xbase + c * HW + w4);
    }
    __syncthreads();

    const int m = blockIdx.y;          // 0=q,1=k,2=v — block-uniform scalar
    const float* Wm = (m == 0) ? Wq : (m == 1) ? Wk : Wv;
    float*       ob = (m == 0) ? qb : (m == 1) ? kb : vb;

    const int w   = t & 63;
    const int sub = __builtin_amdgcn_readfirstlane(t >> 6);  // 0..3, SGPR
    const int o0  = sub * 16;

    float xr[C];
#pragma unroll
    for (int c = 0; c < C; ++c) xr[c] = sx[c][w];

    float* op = ob + b * CHW + o0 * HW + h * W + w;

#pragma unroll
    for (int o = 0; o < 16; ++o) {
        const float* wrow = Wm + (o0 + o) * C;   // scalar address
        float a0 = 0.f, a1 = 0.f, a2 = 0.f, a3 = 0.f;
#pragma unroll
        for (int c = 0; c < C; c += 4) {
            a0 = fmaf(wrow[c + 0], xr[c + 0], a0);
            a1 = fmaf(wrow[c + 1], xr[c + 1], a1);
            a2 = fmaf(wrow[c + 2], xr[c + 2], a2);
            a3 = fmaf(wrow[c + 3], xr[c + 3], a3);
        }
        op[o * HW] = (a0 + a1) + (a2 + a3);
    }
}

// ---------------------------------------------------------------------------
// Pass 2: per-channel 5x5 windowed softmax attention, LDS-staged.
// (byte-identical to round-5 version — kept fixed for clean attribution)
// ---------------------------------------------------------------------------
__global__ __launch_bounds__(256) void attn_kernel(
    const float* __restrict__ qb,
    const float* __restrict__ kb,
    const float* __restrict__ vb,
    const float* __restrict__ rel_h,
    const float* __restrict__ rel_w,
    float* __restrict__ out)
{
    __shared__ __align__(16) float sk[SROWS][SCOLS];
    __shared__ __align__(16) float sv[SROWS][SCOLS];

    const int bid = blockIdx.x;
    const int pl  = bid >> 2;          // b*C + c
    const int h0  = (bid & 3) * TROWS;
    const int c   = pl & 63;
    const int t   = threadIdx.x;

    const float* kp = kb + pl * HW;
    const float* vp = vb + pl * HW;

    // ---- stage: 2 planes * 720 float2 slots ----
    for (int idx = t; idx < 2 * NSLOT2; idx += 256) {
        const int p   = (idx >= NSLOT2);
        const int rem = p ? idx - NSLOT2 : idx;
        const int row = rem / (SCOLS / 2);
        const int c2  = rem - row * (SCOLS / 2);   // float2 col 0..35
        const int g   = h0 + row - PAD;            // global row
        float2 val = make_float2(0.f, 0.f);
        if (((unsigned)g < (unsigned)H) & (c2 >= 1) & (c2 <= 32)) {
            const float* src = (p ? vp : kp) + g * W + (c2 * 2 - 2);
            val = *(const float2*)src;
        }
        float* dst = (p ? &sv[0][0] : &sk[0][0]) + row * SCOLS + c2 * 2;
        *(float2*)dst = val;
    }
    __syncthreads();

    // ---- compute: 1 quad (4 px) per thread ----
    const int lr = t >> 4;             // local row 0..15
    const int w0 = (t & 15) << 2;      // col base 0,4,..,60
    const int h  = h0 + lr;

    const float4 qv = *(const float4*)(qb + pl * HW + h * W + w0);
    const float qx[4] = {qv.x, qv.y, qv.z, qv.w};

    const bool is_h = (c < (C / 2));
    const float* rp = is_h ? (rel_h + c * K) : (rel_w + (c - C / 2) * K);
    float r[K];
#pragma unroll
    for (int u = 0; u < K; ++u) r[u] = rp[u];

    float den[4] = {0.f, 0.f, 0.f, 0.f};
    float num[4] = {0.f, 0.f, 0.f, 0.f};

    if (is_h) {
#pragma unroll
        for (int i = 0; i < K; ++i) {
            const float4 ka = *(const float4*)&sk[lr + i][w0];
            const float4 kc = *(const float4*)&sk[lr + i][w0 + 4];
            const float4 va = *(const float4*)&sv[lr + i][w0];
            const float4 vc = *(const float4*)&sv[lr + i][w0 + 4];
            const float kr[8] = {ka.x, ka.y, ka.z, ka.w, kc.x, kc.y, kc.z, kc.w};
            const float vr[8] = {va.x, va.y, va.z, va.w, vc.x, vc.y, vc.z, vc.w};
            float qri[4];
#pragma unroll
            for (int px = 0; px < 4; ++px) qri[px] = qx[px] * r[i];
#pragma unroll
            for (int j = 0; j < K; ++j) {
#pragma unroll
                for (int px = 0; px < 4; ++px) {
                    const float e = __expf(fmaf(qx[px], kr[px + j], qri[px]));
                    den[px] += e;
                    num[px] = fmaf(e, vr[px + j], num[px]);
                }
            }
        }
    } else {
        float qrj[4][K];
#pragma unroll
        for (int px = 0; px < 4; ++px)
#pragma unroll
            for (int j = 0; j < K; ++j) qrj[px][j] = qx[px] * r[j];
#pragma unroll
        for (int i = 0; i < K; ++i) {
            const float4 ka = *(const float4*)&sk[lr + i][w0];
            const float4 kc = *(const float4*)&sk[lr + i][w0 + 4];
            const float4 va = *(const float4*)&sv[lr + i][w0];
            const float4 vc = *(const float4*)&sv[lr + i][w0 + 4];
            const float kr[8] = {ka.x, ka.y, ka.z, ka.w, kc.x, kc.y, kc.z, kc.w};
            const float vr[8] = {va.x, va.y, va.z, va.w, vc.x, vc.y, vc.z, vc.w};
#pragma unroll
            for (int j = 0; j < K; ++j) {
#pragma unroll
                for (int px = 0; px < 4; ++px) {
                    const float e = __expf(fmaf(qx[px], kr[px + j], qrj[px][j]));
                    den[px] += e;
                    num[px] = fmaf(e, vr[px + j], num[px]);
                }
            }
        }
    }

    float4 o;
    o.x = num[0] * __builtin_amdgcn_rcpf(den[0]);
    o.y = num[1] * __builtin_amdgcn_rcpf(den[1]);
    o.z = num[2] * __builtin_amdgcn_rcpf(den[2]);
    o.w = num[3] * __builtin_amdgcn_rcpf(den[3]);
    *(float4*)(out + pl * HW + h * W + w0) = o;
}

// ---------------------------------------------------------------------------
extern "C" void kernel_launch(void* const* d_in, const int* in_sizes, int n_in,
                              void* d_out, int out_size, void* d_ws, size_t ws_size,
                              hipStream_t stream)
{
    const float* x     = (const float*)d_in[0];
    const float* Wq    = (const float*)d_in[1];
    const float* Wk    = (const float*)d_in[2];
    const float* Wv    = (const float*)d_in[3];
    const float* rel_h = (const float*)d_in[4];
    const float* rel_w = (const float*)d_in[5];

    float* qb = (float*)d_ws;        // [B,C,64,64]  8 MB
    float* kb = qb + TOT;            // [B,C,64,64]  8 MB
    float* vb = kb + TOT;            // [B,C,64,64]  8 MB

    dim3 g1(B * H, 3);
    qkv_kernel<<<g1, 256, 0, stream>>>(x, Wq, Wk, Wv, qb, kb, vb);

    attn_kernel<<<B * C * 4, 256, 0, stream>>>(qb, kb, vb, rel_h, rel_w,
                                               (float*)d_out);
}

// Round 9
// 41.848 us; speedup vs baseline: 1.7282x; 1.0761x over previous
//
#include <hip/hip_runtime.h>

// Problem constants (from reference)
#define B 8
#define C 64
#define H 64
#define W 64
#define K 5
#define PAD 2
#define HW (H * W)          // 4096
#define CHW (C * HW)        // 262144
#define TOT (B * CHW)       // 2097152

// attn tiling: block = 16 rows x 64 cols of one (b,c) plane
#define TROWS 16
#define SROWS (TROWS + 2 * PAD)   // 20 staged rows
#define SCOLS 72                  // 64 + 2*PAD, padded to 72 for 16B row alignment
#define NSLOT2 (SROWS * (SCOLS / 2))  // 720 float2 slots per plane

typedef __attribute__((ext_vector_type(8))) short short8;   // 8 bf16 = 4 VGPR
typedef __attribute__((ext_vector_type(4))) float f32x4;    // mfma accum

__device__ inline unsigned short f2bf(float f) {            // fp32 -> bf16 RNE
    unsigned u = __float_as_uint(f);
    u = u + 0x7fffu + ((u >> 16) & 1u);
    return (unsigned short)(u >> 16);
}
__device__ inline float bf2f(unsigned short h) {
    return __uint_as_float(((unsigned)h) << 16);
}

// ---------------------------------------------------------------------------
// Pass 0: convert Wq|Wk|Wv (fp32 [64][64]) into bf16 hi/lo planes:
// Whl[hl][m][o][c], hl=0 hi, hl=1 lo.  12 blocks x 256 thr, float4-coalesced.
// ---------------------------------------------------------------------------
__global__ __launch_bounds__(256) void wprep_kernel(
    const float* __restrict__ Wq, const float* __restrict__ Wk,
    const float* __restrict__ Wv, unsigned short* __restrict__ Whl)
{
    const int m  = blockIdx.x >> 2;                     // 0..2
    const int f4 = (blockIdx.x & 3) * 256 + threadIdx.x; // float4 id 0..1023
    const float* Wm = (m == 0) ? Wq : (m == 1) ? Wk : Wv;
    const float4 v = ((const float4*)Wm)[f4];
    const float vv[4] = {v.x, v.y, v.z, v.w};
    ushort4 h, l;
    unsigned short* hp = (unsigned short*)&h;
    unsigned short* lp = (unsigned short*)&l;
#pragma unroll
    for (int j = 0; j < 4; ++j) {
        hp[j] = f2bf(vv[j]);
        lp[j] = f2bf(vv[j] - bf2f(hp[j]));
    }
    *(ushort4*)(Whl + m * 4096 + f4 * 4)         = h;   // hi plane
    *(ushort4*)(Whl + (3 + m) * 4096 + f4 * 4)   = l;   // lo plane
}

// ---------------------------------------------------------------------------
// Pass 1 (v5): qkv as MFMA GEMM.  Out[192,HW] = W[192,64] @ x[64,HW] per b,
// fp32 emulated as bf16 hi/lo split: Wh*xh + Wh*xl + Wl*xh (Wl*xl ~2^-18,
// dropped).  Block = (b, 64-col hw-chunk): stage x[64k][64n] fp32 -> bf16
// h/l into LDS [n][k] (row 72 bf16 = 144 B, 16B-aligned frag reads).
// 4 waves x 3 output tiles (16 o) x 4 n-tiles; per D-tile 6 mfma
// (2 k-steps x 3 split products).  Fragment maps (guide §3, HW-verified
// C/D): A lane: row=l&15, k=(l>>4)*8+j; B lane: col=l&15, same k;
// D: col=lane&15 (n), row=(lane>>4)*4+reg (o).  Weights live in 48 VGPRs
// of A-frags -> zero scalar loads in the hot path (r6-r8's stall).
// ---------------------------------------------------------------------------
__global__ __launch_bounds__(256) void qkv_mfma(
    const float* __restrict__ x,
    const unsigned short* __restrict__ Whl,
    float* __restrict__ qb, float* __restrict__ kb, float* __restrict__ vb)
{
    __shared__ unsigned short sxh[64][72];   // [n][k], 9.2 KB
    __shared__ unsigned short sxl[64][72];

    const int bid = blockIdx.x;
    const int b   = bid >> 6;            // 64 chunks per batch
    const int n0  = (bid & 63) * 64;     // hw base
    const int t   = threadIdx.x;

    // ---- stage + convert: 1024 float4, 4 per thread, coalesced ----
    const float* xb = x + b * CHW;
#pragma unroll
    for (int i = 0; i < 4; ++i) {
        const int flat = t + i * 256;        // 0..1023
        const int k    = flat >> 4;          // 16 float4 per k-row
        const int n4   = (flat & 15) << 2;
        const float4 v = *(const float4*)(xb + k * HW + n0 + n4);
        const float vv[4] = {v.x, v.y, v.z, v.w};
#pragma unroll
        for (int j = 0; j < 4; ++j) {
            const unsigned short h = f2bf(vv[j]);
            sxh[n4 + j][k] = h;
            sxl[n4 + j][k] = f2bf(vv[j] - bf2f(h));
        }
    }
    __syncthreads();

    const int lane = t & 63;
    const int wv   = __builtin_amdgcn_readfirstlane(t >> 6);  // wave id 0..3
    const int lr   = lane & 15;          // tile row (A) / col (B,D)
    const int lk   = (lane >> 4) * 8;    // k-group base

    // ---- A fragments: 3 o-tiles x 2 k-steps x {hi,lo} = 48 VGPR ----
    short8 ah[3][2], al[3][2];
#pragma unroll
    for (int ot = 0; ot < 3; ++ot) {
        const int tile = wv * 3 + ot;            // 0..11
        const int m    = tile >> 2;              // 0=q,1=k,2=v
        const int ol0  = (tile & 3) * 16;        // o base within matrix
        const unsigned short* wh = Whl + (m * 64 + ol0 + lr) * 64 + lk;
        const unsigned short* wl = Whl + ((3 + m) * 64 + ol0 + lr) * 64 + lk;
#pragma unroll
        for (int ks = 0; ks < 2; ++ks) {
            ah[ot][ks] = *(const short8*)(wh + ks * 32);
            al[ot][ks] = *(const short8*)(wl + ks * 32);
        }
    }

    f32x4 acc[3][4];
#pragma unroll
    for (int ot = 0; ot < 3; ++ot)
#pragma unroll
        for (int nt = 0; nt < 4; ++nt) acc[ot][nt] = (f32x4)0.f;

#pragma unroll
    for (int nt = 0; nt < 4; ++nt) {
        const short8 bh0 = *(const short8*)&sxh[nt * 16 + lr][lk];
        const short8 bh1 = *(const short8*)&sxh[nt * 16 + lr][32 + lk];
        const short8 bl0 = *(const short8*)&sxl[nt * 16 + lr][lk];
        const short8 bl1 = *(const short8*)&sxl[nt * 16 + lr][32 + lk];
#pragma unroll
        for (int ot = 0; ot < 3; ++ot) {
            f32x4 d = acc[ot][nt];
            d = __builtin_amdgcn_mfma_f32_16x16x32_bf16(ah[ot][0], bh0, d, 0, 0, 0);
            d = __builtin_amdgcn_mfma_f32_16x16x32_bf16(ah[ot][1], bh1, d, 0, 0, 0);
            d = __builtin_amdgcn_mfma_f32_16x16x32_bf16(ah[ot][0], bl0, d, 0, 0, 0);
            d = __builtin_amdgcn_mfma_f32_16x16x32_bf16(ah[ot][1], bl1, d, 0, 0, 0);
            d = __builtin_amdgcn_mfma_f32_16x16x32_bf16(al[ot][0], bh0, d, 0, 0, 0);
            d = __builtin_amdgcn_mfma_f32_16x16x32_bf16(al[ot][1], bh1, d, 0, 0, 0);
            acc[ot][nt] = d;
        }
    }

    // ---- epilogue: D col=lane&15 (n, contiguous stores), row=(lane>>4)*4+r ----
#pragma unroll
    for (int ot = 0; ot < 3; ++ot) {
        const int tile = wv * 3 + ot;
        const int m    = tile >> 2;
        const int ol0  = (tile & 3) * 16;
        float* ob = (m == 0) ? qb : (m == 1) ? kb : vb;
        float* basep = ob + b * CHW + ol0 * HW + n0;
#pragma unroll
        for (int nt = 0; nt < 4; ++nt)
#pragma unroll
            for (int r = 0; r < 4; ++r) {
                const int orow = (lane >> 4) * 4 + r;
                basep[orow * HW + nt * 16 + lr] = acc[ot][nt][r];
            }
    }
}

// ---------------------------------------------------------------------------
// Pass 2: per-channel 5x5 windowed softmax attention, LDS-staged.
// (byte-identical to round-5 version — kept fixed for clean attribution)
// ---------------------------------------------------------------------------
__global__ __launch_bounds__(256) void attn_kernel(
    const float* __restrict__ qb,
    const float* __restrict__ kb,
    const float* __restrict__ vb,
    const float* __restrict__ rel_h,
    const float* __restrict__ rel_w,
    float* __restrict__ out)
{
    __shared__ __align__(16) float sk[SROWS][SCOLS];
    __shared__ __align__(16) float sv[SROWS][SCOLS];

    const int bid = blockIdx.x;
    const int pl  = bid >> 2;          // b*C + c
    const int h0  = (bid & 3) * TROWS;
    const int c   = pl & 63;
    const int t   = threadIdx.x;

    const float* kp = kb + pl * HW;
    const float* vp = vb + pl * HW;

    // ---- stage: 2 planes * 720 float2 slots ----
    for (int idx = t; idx < 2 * NSLOT2; idx += 256) {
        const int p   = (idx >= NSLOT2);
        const int rem = p ? idx - NSLOT2 : idx;
        const int row = rem / (SCOLS / 2);
        const int c2  = rem - row * (SCOLS / 2);   // float2 col 0..35
        const int g   = h0 + row - PAD;            // global row
        float2 val = make_float2(0.f, 0.f);
        if (((unsigned)g < (unsigned)H) & (c2 >= 1) & (c2 <= 32)) {
            const float* src = (p ? vp : kp) + g * W + (c2 * 2 - 2);
            val = *(const float2*)src;
        }
        float* dst = (p ? &sv[0][0] : &sk[0][0]) + row * SCOLS + c2 * 2;
        *(float2*)dst = val;
    }
    __syncthreads();

    // ---- compute: 1 quad (4 px) per thread ----
    const int lr = t >> 4;             // local row 0..15
    const int w0 = (t & 15) << 2;      // col base 0,4,..,60
    const int h  = h0 + lr;

    const float4 qv = *(const float4*)(qb + pl * HW + h * W + w0);
    const float qx[4] = {qv.x, qv.y, qv.z, qv.w};

    const bool is_h = (c < (C / 2));
    const float* rp = is_h ? (rel_h + c * K) : (rel_w + (c - C / 2) * K);
    float r[K];
#pragma unroll
    for (int u = 0; u < K; ++u) r[u] = rp[u];

    float den[4] = {0.f, 0.f, 0.f, 0.f};
    float num[4] = {0.f, 0.f, 0.f, 0.f};

    if (is_h) {
#pragma unroll
        for (int i = 0; i < K; ++i) {
            const float4 ka = *(const float4*)&sk[lr + i][w0];
            const float4 kc = *(const float4*)&sk[lr + i][w0 + 4];
            const float4 va = *(const float4*)&sv[lr + i][w0];
            const float4 vc = *(const float4*)&sv[lr + i][w0 + 4];
            const float kr[8] = {ka.x, ka.y, ka.z, ka.w, kc.x, kc.y, kc.z, kc.w};
            const float vr[8] = {va.x, va.y, va.z, va.w, vc.x, vc.y, vc.z, vc.w};
            float qri[4];
#pragma unroll
            for (int px = 0; px < 4; ++px) qri[px] = qx[px] * r[i];
#pragma unroll
            for (int j = 0; j < K; ++j) {
#pragma unroll
                for (int px = 0; px < 4; ++px) {
                    const float e = __expf(fmaf(qx[px], kr[px + j], qri[px]));
                    den[px] += e;
                    num[px] = fmaf(e, vr[px + j], num[px]);
                }
            }
        }
    } else {
        float qrj[4][K];
#pragma unroll
        for (int px = 0; px < 4; ++px)
#pragma unroll
            for (int j = 0; j < K; ++j) qrj[px][j] = qx[px] * r[j];
#pragma unroll
        for (int i = 0; i < K; ++i) {
            const float4 ka = *(const float4*)&sk[lr + i][w0];
            const float4 kc = *(const float4*)&sk[lr + i][w0 + 4];
            const float4 va = *(const float4*)&sv[lr + i][w0];
            const float4 vc = *(const float4*)&sv[lr + i][w0 + 4];
            const float kr[8] = {ka.x, ka.y, ka.z, ka.w, kc.x, kc.y, kc.z, kc.w};
            const float vr[8] = {va.x, va.y, va.z, va.w, vc.x, vc.y, vc.z, vc.w};
#pragma unroll
            for (int j = 0; j < K; ++j) {
#pragma unroll
                for (int px = 0; px < 4; ++px) {
                    const float e = __expf(fmaf(qx[px], kr[px + j], qrj[px][j]));
                    den[px] += e;
                    num[px] = fmaf(e, vr[px + j], num[px]);
                }
            }
        }
    }

    float4 o;
    o.x = num[0] * __builtin_amdgcn_rcpf(den[0]);
    o.y = num[1] * __builtin_amdgcn_rcpf(den[1]);
    o.z = num[2] * __builtin_amdgcn_rcpf(den[2]);
    o.w = num[3] * __builtin_amdgcn_rcpf(den[3]);
    *(float4*)(out + pl * HW + h * W + w0) = o;
}

// ---------------------------------------------------------------------------
extern "C" void kernel_launch(void* const* d_in, const int* in_sizes, int n_in,
                              void* d_out, int out_size, void* d_ws, size_t ws_size,
                              hipStream_t stream)
{
    const float* x     = (const float*)d_in[0];
    const float* Wq    = (const float*)d_in[1];
    const float* Wk    = (const float*)d_in[2];
    const float* Wv    = (const float*)d_in[3];
    const float* rel_h = (const float*)d_in[4];
    const float* rel_w = (const float*)d_in[5];

    float* qb = (float*)d_ws;        // [B,C,64,64]  8 MB
    float* kb = qb + TOT;            // [B,C,64,64]  8 MB
    float* vb = kb + TOT;            // [B,C,64,64]  8 MB
    unsigned short* Whl = (unsigned short*)(vb + TOT);  // [2][3][64][64] bf16

    wprep_kernel<<<12, 256, 0, stream>>>(Wq, Wk, Wv, Whl);

    qkv_mfma<<<B * 64, 256, 0, stream>>>(x, Whl, qb, kb, vb);

    attn_kernel<<<B * C * 4, 256, 0, stream>>>(qb, kb, vb, rel_h, rel_w,
                                               (float*)d_out);
}